// Round 5
// baseline (1782.494 us; speedup 1.0000x reference)
//
#include <hip/hip_runtime.h>
#include <cstdint>

// BPBookMemory on MI355X (gfx950)
// Plan: sim = (x/||x||)·(m/||m||)^T computed fp32-exactly via bf16 hi/lo split
//       (3 MFMA passes folded into one stacked-K GEMM), top-8 fused in-register,
//       then merge + softmax + gather + axpy in a light epilogue kernel.
// Workspace: A_packed 64MB + B_packed 16MB + cand_score 8MB + cand_idx 8MB = 96MB.
// R3 fix: gm staging pointers now advance with the slot-tile loop (sit) — the
// missing sit*SB*KP term made every slot-tile re-score tile 0 (absmax 0.2998).
// R4: resubmit unchanged (R3 run was lost to GPU acquisition timeout).

typedef __attribute__((ext_vector_type(8))) short short8;
typedef __attribute__((ext_vector_type(16))) float f32x16;

static constexpr int D = 512;
static constexpr int ROWS = 32768;   // 8*4096
static constexpr int SLOTS = 8192;
static constexpr int KP = 1024;      // packed row: [hi(512) | lo(512)] bf16
static constexpr int BM = 128;       // x-rows per block
static constexpr int SHALF = 4096;   // slots per block (grid splits slot dim in 2)
static constexpr int SB = 128;       // slot tile per s-iter
static constexpr int NKC = 48;       // logical K-chunks of 32 (K_eff = 1536)

__device__ __forceinline__ unsigned short f2bf(float f) {
  unsigned u = __float_as_uint(f);
  u += 0x7FFFu + ((u >> 16) & 1u);   // RNE
  return (unsigned short)(u >> 16);
}
__device__ __forceinline__ float bf2f(unsigned short h) {
  return __uint_as_float(((unsigned)h) << 16);
}

// ---------------- prep: L2-normalize rows, split into bf16 hi|lo ----------------
__global__ __launch_bounds__(256) void prep_kernel(const float* __restrict__ x,
                                                   const float* __restrict__ mem,
                                                   unsigned short* __restrict__ Ap,
                                                   unsigned short* __restrict__ Bp) {
  const int w = threadIdx.x >> 6, lane = threadIdx.x & 63;
  const long rid = (long)blockIdx.x * 4 + w;
  const float* src;
  unsigned short* dst;
  if (rid < ROWS) { src = x + rid * D;          dst = Ap + rid * KP; }
  else            { src = mem + (rid - ROWS) * D; dst = Bp + (rid - ROWS) * KP; }
  float4 v0 = *(const float4*)(src + lane * 8);
  float4 v1 = *(const float4*)(src + lane * 8 + 4);
  float ss = v0.x*v0.x + v0.y*v0.y + v0.z*v0.z + v0.w*v0.w
           + v1.x*v1.x + v1.y*v1.y + v1.z*v1.z + v1.w*v1.w;
  #pragma unroll
  for (int m = 1; m < 64; m <<= 1) ss += __shfl_xor(ss, m);
  const float inv = 1.0f / fmaxf(sqrtf(ss), 1e-12f);
  float n[8] = {v0.x*inv, v0.y*inv, v0.z*inv, v0.w*inv,
                v1.x*inv, v1.y*inv, v1.z*inv, v1.w*inv};
  short8 hs, ls;
  #pragma unroll
  for (int j = 0; j < 8; ++j) {
    unsigned short h = f2bf(n[j]);
    hs[j] = (short)h;
    ls[j] = (short)f2bf(n[j] - bf2f(h));
  }
  *(short8*)(dst + lane * 8) = hs;
  *(short8*)(dst + D + lane * 8) = ls;
}

// ---------------- fused GEMM + per-source top-8 ----------------
__device__ __forceinline__ void gload16(const void* g, void* l) {
  __builtin_amdgcn_global_load_lds((const __attribute__((address_space(1))) unsigned int*)g,
                                   (__attribute__((address_space(3))) unsigned int*)l,
                                   16, 0, 0);
}

// sorted-descending top-8 insert; all indices static (register-resident)
__device__ __forceinline__ void insert8(float (&tk)[8], int (&ti)[8], float v, int idx) {
  const bool up0 = v > tk[0];
  #pragma unroll
  for (int j = 7; j >= 1; --j) {
    const bool up = v > tk[j - 1];
    const bool in = v > tk[j];
    const float nv = up ? tk[j - 1] : (in ? v   : tk[j]);
    const int   ni = up ? ti[j - 1] : (in ? idx : ti[j]);
    tk[j] = nv; ti[j] = ni;
  }
  tk[0] = up0 ? v   : tk[0];
  ti[0] = up0 ? idx : ti[0];
}

__global__ __launch_bounds__(256, 2)
void gemm_topk(const unsigned short* __restrict__ Ap,
               const unsigned short* __restrict__ Bp,
               float* __restrict__ cs, int* __restrict__ ci) {
  __shared__ unsigned short x_lds[BM * 32];  // 8 KB, [128 rows][32 k] bf16
  __shared__ unsigned short m_lds[SB * 32];  // 8 KB, [128 slots][32 k] bf16
  const int t = threadIdx.x;
  const int lane = t & 63, w = t >> 6;
  const int wr = w >> 1, ws = w & 1;           // wave grid: 2 row-halves x 2 slot-halves
  const int l31 = lane & 31, g = lane >> 5;
  const int rb = blockIdx.x >> 1, sh = blockIdx.x & 1;
  const int row0 = rb * BM;
  const int slot0 = sh * SHALF;

  // staging pointers: thread t stages chunk t and t+256 of each 8KB tile
  const unsigned short* gx0 = Ap + (long)(row0 + (t >> 2)) * KP + (t & 3) * 8;
  const unsigned short* gx1 = gx0 + 64 * KP;
  const unsigned short* gm0 = Bp + (long)(slot0 + (t >> 2)) * KP + (t & 3) * 8;
  const unsigned short* gm1 = gm0 + 64 * KP;

  float tk0[8], tk1[8]; int ti0[8], ti1[8];
  #pragma unroll
  for (int j = 0; j < 8; ++j) { tk0[j] = -3e38f; tk1[j] = -3e38f; ti0[j] = 0; ti1[j] = 0; }

  for (int sit = 0; sit < SHALF / SB; ++sit) {
    const int stile0 = slot0 + sit * SB;
    const long sofs = (long)sit * SB * KP;   // advance memory staging with slot tile
    f32x16 acc[2][2] = {};
    for (int kc = 0; kc < NKC; ++kc) {
      // stacked-K remap: seg0 hi·hi, seg1 hi_x·lo_m, seg2 lo_x·hi_m
      const int seg = kc >> 4, sub = kc & 15;
      const int ca = (seg == 2 ? 16 + sub : sub) * 32;  // element offset in A row
      const int cb = (seg == 1 ? 16 + sub : sub) * 32;  // element offset in B row
      gload16(gx0 + ca, &x_lds[t * 8]);
      gload16(gx1 + ca, &x_lds[2048 + t * 8]);
      gload16(gm0 + sofs + cb, &m_lds[t * 8]);
      gload16(gm1 + sofs + cb, &m_lds[2048 + t * 8]);
      __syncthreads();   // compiler drains vmcnt before s_barrier -> DMA landed
      short8 af[2][2], bf[2][2];
      #pragma unroll
      for (int si = 0; si < 2; ++si)
        #pragma unroll
        for (int kk = 0; kk < 2; ++kk) {
          af[si][kk] = *(const short8*)&m_lds[(ws * 64 + si * 32 + l31) * 32 + kk * 16 + g * 8];
          bf[si][kk] = *(const short8*)&x_lds[(wr * 64 + si * 32 + l31) * 32 + kk * 16 + g * 8];
        }
      #pragma unroll
      for (int si = 0; si < 2; ++si)
        #pragma unroll
        for (int rj = 0; rj < 2; ++rj)
          #pragma unroll
          for (int kk = 0; kk < 2; ++kk)
            acc[si][rj] = __builtin_amdgcn_mfma_f32_32x32x16_bf16(af[si][kk], bf[rj][kk],
                                                                  acc[si][rj], 0, 0, 0);
      __syncthreads();
    }
    // top-k update; D layout: col(lane&31)=x-row, row=(r&3)+8*(r>>2)+4*g = slot
    #pragma unroll
    for (int si = 0; si < 2; ++si) {
      const int sbase = stile0 + ws * 64 + si * 32 + 4 * g;
      #pragma unroll
      for (int r = 0; r < 16; ++r) {
        const int slot = sbase + (r & 3) + 8 * (r >> 2);
        const float v0 = acc[si][0][r];
        if (v0 > tk0[7]) insert8(tk0, ti0, v0, slot);
        const float v1 = acc[si][1][r];
        if (v1 > tk1[7]) insert8(tk1, ti1, v1, slot);
      }
    }
  }
  // write exact per-source top-8; sources partition slots: src = sh*4 + ws*2 + g
  const int src = sh * 4 + ws * 2 + g;
  const long grow0 = row0 + wr * 64 + l31;   // rj = 0
  const long grow1 = grow0 + 32;             // rj = 1
  float* p0 = cs + grow0 * 64 + src * 8;
  float* p1 = cs + grow1 * 64 + src * 8;
  int*   q0 = ci + grow0 * 64 + src * 8;
  int*   q1 = ci + grow1 * 64 + src * 8;
  #pragma unroll
  for (int j = 0; j < 8; ++j) { p0[j] = tk0[j]; q0[j] = ti0[j]; p1[j] = tk1[j]; q1[j] = ti1[j]; }
}

// ---------------- merge 64 candidates -> top-8, softmax, gather, axpy ----------------
__global__ __launch_bounds__(256)
void merge_out_kernel(const float* __restrict__ cs, const int* __restrict__ ci,
                      const float* __restrict__ x, const float* __restrict__ mem,
                      const float* __restrict__ scale_p, float* __restrict__ out) {
  const int w = threadIdx.x >> 6, lane = threadIdx.x & 63;
  const long row = (long)blockIdx.x * 4 + w;
  float v = cs[row * 64 + lane];
  int idx = ci[row * 64 + lane];
  float pv[8]; int pi[8];
  #pragma unroll
  for (int k = 0; k < 8; ++k) {
    float bv = v; int bi = idx;
    #pragma unroll
    for (int m = 32; m >= 1; m >>= 1) {
      const float ov = __shfl_xor(bv, m);
      const int   oi = __shfl_xor(bi, m);
      if (ov > bv || (ov == bv && oi < bi)) { bv = ov; bi = oi; }
    }
    pv[k] = bv; pi[k] = bi;
    if (idx == bi) v = -3e38f;   // slot indices unique per row -> removes exactly the winner
  }
  float e[8]; float s = 0.f;
  #pragma unroll
  for (int k = 0; k < 8; ++k) { e[k] = expf(pv[k] - pv[0]); s += e[k]; }
  const float wscale = scale_p[0] / s;
  const float* xr = x + row * D + lane * 8;
  float4 o0 = *(const float4*)xr;
  float4 o1 = *(const float4*)(xr + 4);
  #pragma unroll
  for (int k = 0; k < 8; ++k) {
    const float* mr = mem + (long)pi[k] * D + lane * 8;
    const float4 m0 = *(const float4*)mr;
    const float4 m1 = *(const float4*)(mr + 4);
    const float a = e[k] * wscale;
    o0.x += a * m0.x; o0.y += a * m0.y; o0.z += a * m0.z; o0.w += a * m0.w;
    o1.x += a * m1.x; o1.y += a * m1.y; o1.z += a * m1.z; o1.w += a * m1.w;
  }
  float* orow = out + row * D + lane * 8;
  *(float4*)orow = o0;
  *(float4*)(orow + 4) = o1;
}

extern "C" void kernel_launch(void* const* d_in, const int* in_sizes, int n_in,
                              void* d_out, int out_size, void* d_ws, size_t ws_size,
                              hipStream_t stream) {
  const float* x       = (const float*)d_in[0];
  const float* mem     = (const float*)d_in[1];
  const float* scale_p = (const float*)d_in[2];
  float* out = (float*)d_out;
  char* ws = (char*)d_ws;
  // requires ws_size >= 96 MB
  unsigned short* Ap = (unsigned short*)ws;                                  // 64 MB
  unsigned short* Bp = (unsigned short*)(ws + (size_t)67108864);             // 16 MB
  float* cs = (float*)(ws + (size_t)67108864 + 16777216);                    //  8 MB
  int*   ci = (int*)  (ws + (size_t)67108864 + 16777216 + 8388608);          //  8 MB

  hipLaunchKernelGGL(prep_kernel, dim3((ROWS + SLOTS) / 4), dim3(256), 0, stream, x, mem, Ap, Bp);
  hipLaunchKernelGGL(gemm_topk, dim3(512), dim3(256), 0, stream, Ap, Bp, cs, ci);
  hipLaunchKernelGGL(merge_out_kernel, dim3(ROWS / 4), dim3(256), 0, stream, cs, ci, x, mem, scale_p, out);
}

// Round 6
// 1629.932 us; speedup vs baseline: 1.0936x; 1.0936x over previous
//
#include <hip/hip_runtime.h>
#include <cstdint>

// BPBookMemory on MI355X (gfx950)
// sim = (x/||x||)·(m/||m||)^T fp32-exact via bf16 hi/lo split (3 MFMA passes
// folded into stacked-K GEMM), top-8 fused in-register, merge/softmax/gather epilogue.
// Workspace: A_packed 64MB + B_packed 16MB + cand_score 8MB + cand_idx 8MB = 96MB.
// R5: LDS chunk swizzle (T2 adapted): slot(row,j) holds global chunk (j-(row>>1))&3,
// read at j=((c+(row>>1))&3). Pre-swizzled GLOBAL source + linear gload_lds dest +
// swizzled ds_read (rule #21). R5 counters: 3.02e8 bank-conflict cycles ≈ 45% of
// kernel time; lanes previously 16-way conflicted on 64B-row chunk reads.

typedef __attribute__((ext_vector_type(8))) short short8;
typedef __attribute__((ext_vector_type(16))) float f32x16;

static constexpr int D = 512;
static constexpr int ROWS = 32768;   // 8*4096
static constexpr int SLOTS = 8192;
static constexpr int KP = 1024;      // packed row: [hi(512) | lo(512)] bf16
static constexpr int BM = 128;       // x-rows per block
static constexpr int SHALF = 4096;   // slots per block (grid splits slot dim in 2)
static constexpr int SB = 128;       // slot tile per s-iter
static constexpr int NKC = 48;       // logical K-chunks of 32 (K_eff = 1536)

__device__ __forceinline__ unsigned short f2bf(float f) {
  unsigned u = __float_as_uint(f);
  u += 0x7FFFu + ((u >> 16) & 1u);   // RNE
  return (unsigned short)(u >> 16);
}
__device__ __forceinline__ float bf2f(unsigned short h) {
  return __uint_as_float(((unsigned)h) << 16);
}

// ---------------- prep: L2-normalize rows, split into bf16 hi|lo ----------------
__global__ __launch_bounds__(256) void prep_kernel(const float* __restrict__ x,
                                                   const float* __restrict__ mem,
                                                   unsigned short* __restrict__ Ap,
                                                   unsigned short* __restrict__ Bp) {
  const int w = threadIdx.x >> 6, lane = threadIdx.x & 63;
  const long rid = (long)blockIdx.x * 4 + w;
  const float* src;
  unsigned short* dst;
  if (rid < ROWS) { src = x + rid * D;          dst = Ap + rid * KP; }
  else            { src = mem + (rid - ROWS) * D; dst = Bp + (rid - ROWS) * KP; }
  float4 v0 = *(const float4*)(src + lane * 8);
  float4 v1 = *(const float4*)(src + lane * 8 + 4);
  float ss = v0.x*v0.x + v0.y*v0.y + v0.z*v0.z + v0.w*v0.w
           + v1.x*v1.x + v1.y*v1.y + v1.z*v1.z + v1.w*v1.w;
  #pragma unroll
  for (int m = 1; m < 64; m <<= 1) ss += __shfl_xor(ss, m);
  const float inv = 1.0f / fmaxf(sqrtf(ss), 1e-12f);
  float n[8] = {v0.x*inv, v0.y*inv, v0.z*inv, v0.w*inv,
                v1.x*inv, v1.y*inv, v1.z*inv, v1.w*inv};
  short8 hs, ls;
  #pragma unroll
  for (int j = 0; j < 8; ++j) {
    unsigned short h = f2bf(n[j]);
    hs[j] = (short)h;
    ls[j] = (short)f2bf(n[j] - bf2f(h));
  }
  *(short8*)(dst + lane * 8) = hs;
  *(short8*)(dst + D + lane * 8) = ls;
}

// ---------------- fused GEMM + per-source top-8 ----------------
__device__ __forceinline__ void gload16(const void* g, void* l) {
  __builtin_amdgcn_global_load_lds((const __attribute__((address_space(1))) unsigned int*)g,
                                   (__attribute__((address_space(3))) unsigned int*)l,
                                   16, 0, 0);
}

// sorted-descending top-8 insert; all indices static (register-resident)
__device__ __forceinline__ void insert8(float (&tk)[8], int (&ti)[8], float v, int idx) {
  const bool up0 = v > tk[0];
  #pragma unroll
  for (int j = 7; j >= 1; --j) {
    const bool up = v > tk[j - 1];
    const bool in = v > tk[j];
    const float nv = up ? tk[j - 1] : (in ? v   : tk[j]);
    const int   ni = up ? ti[j - 1] : (in ? idx : ti[j]);
    tk[j] = nv; ti[j] = ni;
  }
  tk[0] = up0 ? v   : tk[0];
  ti[0] = up0 ? idx : ti[0];
}

__global__ __launch_bounds__(256, 2)
void gemm_topk(const unsigned short* __restrict__ Ap,
               const unsigned short* __restrict__ Bp,
               float* __restrict__ cs, int* __restrict__ ci) {
  __shared__ unsigned short x_lds[BM * 32];  // 8 KB, slot(r,j) = 16B chunks, swizzled
  __shared__ unsigned short m_lds[SB * 32];  // 8 KB
  const int t = threadIdx.x;
  const int lane = t & 63, w = t >> 6;
  const int wr = w >> 1, ws = w & 1;           // wave grid: 2 row-halves x 2 slot-halves
  const int l31 = lane & 31, g = lane >> 5;
  const int rb = blockIdx.x >> 1, sh = blockIdx.x & 1;
  const int row0 = rb * BM;
  const int slot0 = sh * SHALF;

  // staging: thread t fills LDS slot t (bytes 16t..16t+15) and slot 256+t.
  // slot s -> (row = s>>2, j = s&3) holds global chunk c = (j - (row>>1)) & 3.
  // For both s=t and s=256+t: c = ((t&3) - (t>>3)) & 3  (256+t preserves it mod 4).
  const int cswz = (((t & 3) - (t >> 3)) & 3) * 8;   // element offset of swizzled chunk
  const unsigned short* gx0 = Ap + (long)(row0 + (t >> 2)) * KP + cswz;
  const unsigned short* gx1 = gx0 + 64 * KP;
  const unsigned short* gm0 = Bp + (long)(slot0 + (t >> 2)) * KP + cswz;
  const unsigned short* gm1 = gm0 + 64 * KP;

  float tk0[8], tk1[8]; int ti0[8], ti1[8];
  #pragma unroll
  for (int j = 0; j < 8; ++j) { tk0[j] = -3e38f; tk1[j] = -3e38f; ti0[j] = 0; ti1[j] = 0; }

  for (int sit = 0; sit < SHALF / SB; ++sit) {
    const int stile0 = slot0 + sit * SB;
    const long sofs = (long)sit * SB * KP;   // advance memory staging with slot tile
    f32x16 acc[2][2] = {};
    for (int kc = 0; kc < NKC; ++kc) {
      // stacked-K remap: seg0 hi·hi, seg1 hi_x·lo_m, seg2 lo_x·hi_m
      const int seg = kc >> 4, sub = kc & 15;
      const int ca = (seg == 2 ? 16 + sub : sub) * 32;  // element offset in A row
      const int cb = (seg == 1 ? 16 + sub : sub) * 32;  // element offset in B row
      gload16(gx0 + ca, &x_lds[t * 8]);
      gload16(gx1 + ca, &x_lds[2048 + t * 8]);
      gload16(gm0 + sofs + cb, &m_lds[t * 8]);
      gload16(gm1 + sofs + cb, &m_lds[2048 + t * 8]);
      __syncthreads();   // compiler drains vmcnt before s_barrier -> DMA landed
      short8 af[2][2], bf[2][2];
      #pragma unroll
      for (int si = 0; si < 2; ++si) {
        const int rm = ws * 64 + si * 32 + l31;          // m-row in tile
        const int rx = wr * 64 + si * 32 + l31;          // x-row in tile
        #pragma unroll
        for (int kk = 0; kk < 2; ++kk) {
          const int cm = ((kk * 2 + g) + (rm >> 1)) & 3; // swizzled chunk position
          const int cx = ((kk * 2 + g) + (rx >> 1)) & 3;
          af[si][kk] = *(const short8*)&m_lds[rm * 32 + cm * 8];
          bf[si][kk] = *(const short8*)&x_lds[rx * 32 + cx * 8];
        }
      }
      #pragma unroll
      for (int si = 0; si < 2; ++si)
        #pragma unroll
        for (int rj = 0; rj < 2; ++rj)
          #pragma unroll
          for (int kk = 0; kk < 2; ++kk)
            acc[si][rj] = __builtin_amdgcn_mfma_f32_32x32x16_bf16(af[si][kk], bf[rj][kk],
                                                                  acc[si][rj], 0, 0, 0);
      __syncthreads();
    }
    // top-k update; D layout: col(lane&31)=x-row, row=(r&3)+8*(r>>2)+4*g = slot
    #pragma unroll
    for (int si = 0; si < 2; ++si) {
      const int sbase = stile0 + ws * 64 + si * 32 + 4 * g;
      #pragma unroll
      for (int r = 0; r < 16; ++r) {
        const int slot = sbase + (r & 3) + 8 * (r >> 2);
        const float v0 = acc[si][0][r];
        if (v0 > tk0[7]) insert8(tk0, ti0, v0, slot);
        const float v1 = acc[si][1][r];
        if (v1 > tk1[7]) insert8(tk1, ti1, v1, slot);
      }
    }
  }
  // write exact per-source top-8; sources partition slots: src = sh*4 + ws*2 + g
  const int src = sh * 4 + ws * 2 + g;
  const long grow0 = row0 + wr * 64 + l31;   // rj = 0
  const long grow1 = grow0 + 32;             // rj = 1
  float* p0 = cs + grow0 * 64 + src * 8;
  float* p1 = cs + grow1 * 64 + src * 8;
  int*   q0 = ci + grow0 * 64 + src * 8;
  int*   q1 = ci + grow1 * 64 + src * 8;
  #pragma unroll
  for (int j = 0; j < 8; ++j) { p0[j] = tk0[j]; q0[j] = ti0[j]; p1[j] = tk1[j]; q1[j] = ti1[j]; }
}

// ---------------- merge 64 candidates -> top-8, softmax, gather, axpy ----------------
__global__ __launch_bounds__(256)
void merge_out_kernel(const float* __restrict__ cs, const int* __restrict__ ci,
                      const float* __restrict__ x, const float* __restrict__ mem,
                      const float* __restrict__ scale_p, float* __restrict__ out) {
  const int w = threadIdx.x >> 6, lane = threadIdx.x & 63;
  const long row = (long)blockIdx.x * 4 + w;
  float v = cs[row * 64 + lane];
  int idx = ci[row * 64 + lane];
  float pv[8]; int pi[8];
  #pragma unroll
  for (int k = 0; k < 8; ++k) {
    float bv = v; int bi = idx;
    #pragma unroll
    for (int m = 32; m >= 1; m >>= 1) {
      const float ov = __shfl_xor(bv, m);
      const int   oi = __shfl_xor(bi, m);
      if (ov > bv || (ov == bv && oi < bi)) { bv = ov; bi = oi; }
    }
    pv[k] = bv; pi[k] = bi;
    if (idx == bi) v = -3e38f;   // slot indices unique per row -> removes exactly the winner
  }
  float e[8]; float s = 0.f;
  #pragma unroll
  for (int k = 0; k < 8; ++k) { e[k] = expf(pv[k] - pv[0]); s += e[k]; }
  const float wscale = scale_p[0] / s;
  const float* xr = x + row * D + lane * 8;
  float4 o0 = *(const float4*)xr;
  float4 o1 = *(const float4*)(xr + 4);
  #pragma unroll
  for (int k = 0; k < 8; ++k) {
    const float* mr = mem + (long)pi[k] * D + lane * 8;
    const float4 m0 = *(const float4*)mr;
    const float4 m1 = *(const float4*)(mr + 4);
    const float a = e[k] * wscale;
    o0.x += a * m0.x; o0.y += a * m0.y; o0.z += a * m0.z; o0.w += a * m0.w;
    o1.x += a * m1.x; o1.y += a * m1.y; o1.z += a * m1.z; o1.w += a * m1.w;
  }
  float* orow = out + row * D + lane * 8;
  *(float4*)orow = o0;
  *(float4*)(orow + 4) = o1;
}

extern "C" void kernel_launch(void* const* d_in, const int* in_sizes, int n_in,
                              void* d_out, int out_size, void* d_ws, size_t ws_size,
                              hipStream_t stream) {
  const float* x       = (const float*)d_in[0];
  const float* mem     = (const float*)d_in[1];
  const float* scale_p = (const float*)d_in[2];
  float* out = (float*)d_out;
  char* ws = (char*)d_ws;
  // requires ws_size >= 96 MB
  unsigned short* Ap = (unsigned short*)ws;                                  // 64 MB
  unsigned short* Bp = (unsigned short*)(ws + (size_t)67108864);             // 16 MB
  float* cs = (float*)(ws + (size_t)67108864 + 16777216);                    //  8 MB
  int*   ci = (int*)  (ws + (size_t)67108864 + 16777216 + 8388608);          //  8 MB

  hipLaunchKernelGGL(prep_kernel, dim3((ROWS + SLOTS) / 4), dim3(256), 0, stream, x, mem, Ap, Bp);
  hipLaunchKernelGGL(gemm_topk, dim3(512), dim3(256), 0, stream, Ap, Bp, cs, ci);
  hipLaunchKernelGGL(merge_out_kernel, dim3(ROWS / 4), dim3(256), 0, stream, cs, ci, x, mem, scale_p, out);
}

// Round 7
// 1083.585 us; speedup vs baseline: 1.6450x; 1.5042x over previous
//
#include <hip/hip_runtime.h>
#include <cstdint>

// BPBookMemory on MI355X (gfx950)
// R7: single-pass bf16 GEMM (K=512) for candidate scores + exact fp32 rescore
// of merged top-16 in the epilogue. Replaces the 3-pass hi/lo split (R5/R6
// counters: LDS-throughput-bound at reads/MFMA=1.0, 68% LDS busy — 3x K was
// 3x LDS traffic). T2 chunk swizzle kept (conflicts at b128 floor: +4cyc/read).
// Workspace: MN 16MB @0 | Ap 32MB @16MB | Bp 8MB @48MB | cs 8MB @56MB | ci 8MB @64MB.

typedef __attribute__((ext_vector_type(8))) short short8;
typedef __attribute__((ext_vector_type(16))) float f32x16;

static constexpr int D = 512;
static constexpr int ROWS = 32768;   // 8*4096
static constexpr int SLOTS = 8192;
static constexpr int BM = 128;       // x-rows per block
static constexpr int SHALF = 4096;   // slots per block (grid splits slot dim in 2)
static constexpr int SB = 128;       // slot tile per s-iter
static constexpr int NKC = 16;       // K-chunks of 32 (K = 512, single pass)

__device__ __forceinline__ unsigned short f2bf(float f) {
  unsigned u = __float_as_uint(f);
  u += 0x7FFFu + ((u >> 16) & 1u);   // RNE
  return (unsigned short)(u >> 16);
}

// ---------------- prep: L2-normalize rows; bf16 copies + fp32 mem_norm ----------------
__global__ __launch_bounds__(256) void prep_kernel(const float* __restrict__ x,
                                                   const float* __restrict__ mem,
                                                   unsigned short* __restrict__ Ap,
                                                   unsigned short* __restrict__ Bp,
                                                   float* __restrict__ MN) {
  const int w = threadIdx.x >> 6, lane = threadIdx.x & 63;
  const long rid = (long)blockIdx.x * 4 + w;
  const float* src = (rid < ROWS) ? (x + rid * D) : (mem + (rid - ROWS) * D);
  float4 v0 = *(const float4*)(src + lane * 8);
  float4 v1 = *(const float4*)(src + lane * 8 + 4);
  float ss = v0.x*v0.x + v0.y*v0.y + v0.z*v0.z + v0.w*v0.w
           + v1.x*v1.x + v1.y*v1.y + v1.z*v1.z + v1.w*v1.w;
  #pragma unroll
  for (int m = 1; m < 64; m <<= 1) ss += __shfl_xor(ss, m);
  const float inv = 1.0f / fmaxf(sqrtf(ss), 1e-12f);
  float n[8] = {v0.x*inv, v0.y*inv, v0.z*inv, v0.w*inv,
                v1.x*inv, v1.y*inv, v1.z*inv, v1.w*inv};
  short8 hs;
  #pragma unroll
  for (int j = 0; j < 8; ++j) hs[j] = (short)f2bf(n[j]);
  if (rid < ROWS) {
    *(short8*)(Ap + rid * D + lane * 8) = hs;
  } else {
    const long mrow = rid - ROWS;
    *(short8*)(Bp + mrow * D + lane * 8) = hs;
    float* mnr = MN + mrow * D + lane * 8;
    *(float4*)mnr = make_float4(n[0], n[1], n[2], n[3]);
    *(float4*)(mnr + 4) = make_float4(n[4], n[5], n[6], n[7]);
  }
}

// ---------------- fused GEMM + per-source top-8 (bf16-score candidates) ----------------
__device__ __forceinline__ void gload16(const void* g, void* l) {
  __builtin_amdgcn_global_load_lds((const __attribute__((address_space(1))) unsigned int*)g,
                                   (__attribute__((address_space(3))) unsigned int*)l,
                                   16, 0, 0);
}

// sorted-descending top-8 insert; all indices static (register-resident)
__device__ __forceinline__ void insert8(float (&tk)[8], int (&ti)[8], float v, int idx) {
  const bool up0 = v > tk[0];
  #pragma unroll
  for (int j = 7; j >= 1; --j) {
    const bool up = v > tk[j - 1];
    const bool in = v > tk[j];
    const float nv = up ? tk[j - 1] : (in ? v   : tk[j]);
    const int   ni = up ? ti[j - 1] : (in ? idx : ti[j]);
    tk[j] = nv; ti[j] = ni;
  }
  tk[0] = up0 ? v   : tk[0];
  ti[0] = up0 ? idx : ti[0];
}

__global__ __launch_bounds__(256, 2)
void gemm_topk(const unsigned short* __restrict__ Ap,
               const unsigned short* __restrict__ Bp,
               float* __restrict__ cs, int* __restrict__ ci) {
  __shared__ unsigned short x_lds[BM * 32];  // 8 KB, 16B chunks, T2-swizzled
  __shared__ unsigned short m_lds[SB * 32];  // 8 KB
  const int t = threadIdx.x;
  const int lane = t & 63, w = t >> 6;
  const int wr = w >> 1, ws = w & 1;           // wave grid: 2 row-halves x 2 slot-halves
  const int l31 = lane & 31, g = lane >> 5;
  const int rb = blockIdx.x >> 1, sh = blockIdx.x & 1;
  const int row0 = rb * BM;
  const int slot0 = sh * SHALF;

  // staging: thread t fills LDS slot t and slot 256+t (16B each).
  // slot s -> (row=s>>2, j=s&3) holds global chunk c = (j - (row>>1)) & 3.
  const int cswz = (((t & 3) - (t >> 3)) & 3) * 8;   // element offset of swizzled chunk
  const unsigned short* gx0 = Ap + (long)(row0 + (t >> 2)) * D + cswz;
  const unsigned short* gx1 = gx0 + 64 * D;
  const unsigned short* gm0 = Bp + (long)(slot0 + (t >> 2)) * D + cswz;
  const unsigned short* gm1 = gm0 + 64 * D;

  float tk0[8], tk1[8]; int ti0[8], ti1[8];
  #pragma unroll
  for (int j = 0; j < 8; ++j) { tk0[j] = -3e38f; tk1[j] = -3e38f; ti0[j] = 0; ti1[j] = 0; }

  for (int sit = 0; sit < SHALF / SB; ++sit) {
    const int stile0 = slot0 + sit * SB;
    const long sofs = (long)sit * SB * D;   // advance memory staging with slot tile
    f32x16 acc[2][2] = {};
    for (int kc = 0; kc < NKC; ++kc) {
      const int c = kc * 32;               // K-chunk element offset
      gload16(gx0 + c, &x_lds[t * 8]);
      gload16(gx1 + c, &x_lds[2048 + t * 8]);
      gload16(gm0 + sofs + c, &m_lds[t * 8]);
      gload16(gm1 + sofs + c, &m_lds[2048 + t * 8]);
      __syncthreads();   // compiler drains vmcnt before s_barrier -> DMA landed
      short8 af[2][2], bf[2][2];
      #pragma unroll
      for (int si = 0; si < 2; ++si) {
        const int rm = ws * 64 + si * 32 + l31;          // m-row in tile
        const int rx = wr * 64 + si * 32 + l31;          // x-row in tile
        #pragma unroll
        for (int kk = 0; kk < 2; ++kk) {
          const int cm = ((kk * 2 + g) + (rm >> 1)) & 3; // swizzled chunk position
          const int cx = ((kk * 2 + g) + (rx >> 1)) & 3;
          af[si][kk] = *(const short8*)&m_lds[rm * 32 + cm * 8];
          bf[si][kk] = *(const short8*)&x_lds[rx * 32 + cx * 8];
        }
      }
      #pragma unroll
      for (int si = 0; si < 2; ++si)
        #pragma unroll
        for (int rj = 0; rj < 2; ++rj)
          #pragma unroll
          for (int kk = 0; kk < 2; ++kk)
            acc[si][rj] = __builtin_amdgcn_mfma_f32_32x32x16_bf16(af[si][kk], bf[rj][kk],
                                                                  acc[si][rj], 0, 0, 0);
      __syncthreads();
    }
    // top-k update; D layout: col(lane&31)=x-row, row=(r&3)+8*(r>>2)+4*g = slot
    #pragma unroll
    for (int si = 0; si < 2; ++si) {
      const int sbase = stile0 + ws * 64 + si * 32 + 4 * g;
      #pragma unroll
      for (int r = 0; r < 16; ++r) {
        const int slot = sbase + (r & 3) + 8 * (r >> 2);
        const float v0 = acc[si][0][r];
        if (v0 > tk0[7]) insert8(tk0, ti0, v0, slot);
        const float v1 = acc[si][1][r];
        if (v1 > tk1[7]) insert8(tk1, ti1, v1, slot);
      }
    }
  }
  // write exact per-source top-8; sources partition slots: src = sh*4 + ws*2 + g
  const int src = sh * 4 + ws * 2 + g;
  const long grow0 = row0 + wr * 64 + l31;   // rj = 0
  const long grow1 = grow0 + 32;             // rj = 1
  float* p0 = cs + grow0 * 64 + src * 8;
  float* p1 = cs + grow1 * 64 + src * 8;
  int*   q0 = ci + grow0 * 64 + src * 8;
  int*   q1 = ci + grow1 * 64 + src * 8;
  #pragma unroll
  for (int j = 0; j < 8; ++j) { p0[j] = tk0[j]; q0[j] = ti0[j]; p1[j] = tk1[j]; q1[j] = ti1[j]; }
}

// ---- merge 64 bf16-scored candidates -> top-16 -> exact rescore -> top-8 -> out ----
__global__ __launch_bounds__(256)
void merge_out_kernel(const float* __restrict__ cs, const int* __restrict__ ci,
                      const float* __restrict__ x, const float* __restrict__ mem,
                      const float* __restrict__ MN, const float* __restrict__ scale_p,
                      float* __restrict__ out) {
  const int w = threadIdx.x >> 6, lane = threadIdx.x & 63;
  const long row = (long)blockIdx.x * 4 + w;
  float v = cs[row * 64 + lane];
  int idx = ci[row * 64 + lane];
  // x row (kept for rescore and final axpy) + its inverse norm
  const float* xr = x + row * D + lane * 8;
  const float4 x0 = *(const float4*)xr;
  const float4 x1 = *(const float4*)(xr + 4);
  float ss = x0.x*x0.x + x0.y*x0.y + x0.z*x0.z + x0.w*x0.w
           + x1.x*x1.x + x1.y*x1.y + x1.z*x1.z + x1.w*x1.w;
  #pragma unroll
  for (int m = 1; m < 64; m <<= 1) ss += __shfl_xor(ss, m);
  const float inv = 1.0f / fmaxf(sqrtf(ss), 1e-12f);
  // select top-16 of 64 by bf16-pass score (butterfly argmax, low-idx tie-break)
  int sel[16];
  #pragma unroll
  for (int k = 0; k < 16; ++k) {
    float bv = v; int bi = idx;
    #pragma unroll
    for (int m = 32; m >= 1; m >>= 1) {
      const float ov = __shfl_xor(bv, m);
      const int   oi = __shfl_xor(bi, m);
      if (ov > bv || (ov == bv && oi < bi)) { bv = ov; bi = oi; }
    }
    sel[k] = bi;
    if (idx == bi) v = -3e38f;   // candidates unique per row -> removes the winner
  }
  // exact fp32 rescore: score = (x . mem_norm[s]) * inv||x||
  float es[16];
  #pragma unroll
  for (int k = 0; k < 16; ++k) {
    const float* mr = MN + (long)sel[k] * D + lane * 8;
    const float4 a = *(const float4*)mr;
    const float4 b = *(const float4*)(mr + 4);
    float p = x0.x*a.x + x0.y*a.y + x0.z*a.z + x0.w*a.w
            + x1.x*b.x + x1.y*b.y + x1.z*b.z + x1.w*b.w;
    #pragma unroll
    for (int m = 1; m < 64; m <<= 1) p += __shfl_xor(p, m);
    es[k] = p * inv;
  }
  // exact top-8 of the 16
  float tk[8]; int ti[8];
  #pragma unroll
  for (int j = 0; j < 8; ++j) { tk[j] = -3e38f; ti[j] = 0; }
  #pragma unroll
  for (int k = 0; k < 16; ++k)
    if (es[k] > tk[7]) insert8(tk, ti, es[k], sel[k]);
  // softmax (tk[0] is max), weighted gather of RAW memory, axpy
  float e[8]; float s = 0.f;
  #pragma unroll
  for (int k = 0; k < 8; ++k) { e[k] = expf(tk[k] - tk[0]); s += e[k]; }
  const float wscale = scale_p[0] / s;
  float4 o0 = x0, o1 = x1;
  #pragma unroll
  for (int k = 0; k < 8; ++k) {
    const float* mr = mem + (long)ti[k] * D + lane * 8;
    const float4 m0 = *(const float4*)mr;
    const float4 m1 = *(const float4*)(mr + 4);
    const float a = e[k] * wscale;
    o0.x += a * m0.x; o0.y += a * m0.y; o0.z += a * m0.z; o0.w += a * m0.w;
    o1.x += a * m1.x; o1.y += a * m1.y; o1.z += a * m1.z; o1.w += a * m1.w;
  }
  float* orow = out + row * D + lane * 8;
  *(float4*)orow = o0;
  *(float4*)(orow + 4) = o1;
}

extern "C" void kernel_launch(void* const* d_in, const int* in_sizes, int n_in,
                              void* d_out, int out_size, void* d_ws, size_t ws_size,
                              hipStream_t stream) {
  const float* x       = (const float*)d_in[0];
  const float* mem     = (const float*)d_in[1];
  const float* scale_p = (const float*)d_in[2];
  float* out = (float*)d_out;
  char* ws = (char*)d_ws;
  // requires ws_size >= 72 MB
  float*          MN = (float*)ws;                                   // 16 MB
  unsigned short* Ap = (unsigned short*)(ws + (size_t)16777216);     // 32 MB
  unsigned short* Bp = (unsigned short*)(ws + (size_t)50331648);     //  8 MB
  float*          cs = (float*)(ws + (size_t)58720256);              //  8 MB
  int*            ci = (int*)  (ws + (size_t)67108864);              //  8 MB

  hipLaunchKernelGGL(prep_kernel, dim3((ROWS + SLOTS) / 4), dim3(256), 0, stream,
                     x, mem, Ap, Bp, MN);
  hipLaunchKernelGGL(gemm_topk, dim3(512), dim3(256), 0, stream, Ap, Bp, cs, ci);
  hipLaunchKernelGGL(merge_out_kernel, dim3(ROWS / 4), dim3(256), 0, stream,
                     cs, ci, x, mem, MN, scale_p, out);
}